// Round 5
// baseline (274.514 us; speedup 1.0000x reference)
//
#include <hip/hip_runtime.h>
#include <math.h>

#define PATCH   32
#define NBINS   36
#define WPB     4           // waves (patches) per block
#define HW_N    (PATCH*PATCH)
#define TR      34          // padded rows (rows 0..33; interior 1..32)
#define TC      35          // padded row stride in f64 (cols 0..33 used)

// phi = atan2(gy, gx+1e-18) * 18/pi in (-18,18]; bin = (54+floor(phi))%36,
// w1 = frac(phi). n = nearest 10-deg sector from f32 estimate (err ~0.009
// sector); exact f64 rotation by -n*10deg; sin(delta) = y'*rsqrt(m2);
// delta via deg-9 odd asin series (|delta| <= ~5.1deg). Total bin error
// ~1e-13; floor() absorbs estimate error; boundary flips weight-continuous.

__global__ __launch_bounds__(256, 2) void patch_dom_orient_kernel(
    const float* __restrict__ patch,
    const float* __restrict__ wk,
    const float* __restrict__ sw,
    float* __restrict__ out,
    int num_patches)
{
    __shared__ double tile[WPB][TR][TC];       // f64, edge-padded
    __shared__ double wkl[HW_N];               // wk * 0.125, f64 (per block)
    __shared__ double hist[WPB][2][NBINS];     // 2-way replicated
    __shared__ double hsm [WPB][NBINS];
    __shared__ double ctab[37];
    __shared__ double stab[37];

    const int tid  = threadIdx.x;
    const int w    = tid >> 6;
    const int lane = tid & 63;
    const int p    = blockIdx.x * WPB + w;
    const int pc   = (p < num_patches) ? p : (num_patches - 1);

    // ---- zero replicated histograms (72 doubles per wave) ----
    {
        double* hf = &hist[w][0][0];
        hf[lane] = 0.0;                 // 0..63
        if (lane < 8) hf[64 + lane] = 0.0;
    }
    // ---- sector sin/cos table (per block) ----
    if (tid < 37) {
        double a = ((double)tid - 18.0) * 0.17453292519943295;  // pi/18
        ctab[tid] = cos(a);
        stab[tid] = sin(a);
    }
    // ---- stage wk * 0.125 as f64 (256 threads x float4) ----
    {
        float4 v = reinterpret_cast<const float4*>(wk)[tid];
        double* dst = &wkl[tid * 4];
        dst[0] = (double)v.x * 0.125;
        dst[1] = (double)v.y * 0.125;
        dst[2] = (double)v.z * 0.125;
        dst[3] = (double)v.w * 0.125;
    }
    // ---- stage patch as f64 into padded tile interior ----
    const float4* pp4 = reinterpret_cast<const float4*>(patch + (size_t)pc * HW_N);
    #pragma unroll
    for (int i = 0; i < 4; ++i) {
        int idx4 = i * 64 + lane;            // 0..255
        float4 v = pp4[idx4];
        int flat = idx4 * 4;
        int row = flat >> 5;                 // 0..31
        int col = flat & 31;                 // 0,4,...,28
        double* dst = &tile[w][row + 1][col + 1];
        dst[0] = (double)v.x;
        dst[1] = (double)v.y;
        dst[2] = (double)v.z;
        dst[3] = (double)v.w;
    }
    // ---- edge duplication (clamp semantics), same wave so in-order ----
    {
        int r = (lane >> 1) + 1;             // 1..32
        if (lane & 1) tile[w][r][33] = tile[w][r][32];
        else          tile[w][r][0]  = tile[w][r][1];
    }
    if (lane < 34) tile[w][0][lane]  = tile[w][1][lane];
    if (lane < 34) tile[w][33][lane] = tile[w][32][lane];
    __syncthreads();

    // ---- per-pixel: padded f64 Sobel, sector-rotated asin angle, scatter ----
    #pragma unroll 2
    for (int i = 0; i < HW_N / 64; ++i) {
        int idx = i * 64 + lane;
        int y = idx >> 5, x = idx & 31;
        const double* c0 = &tile[w][y + 1][x + 1];

        double pmm = c0[-TC - 1], pm0 = c0[-TC], pmp = c0[-TC + 1];
        double p0m = c0[-1],                     p0p = c0[1];
        double ppm = c0[ TC - 1], pp0 = c0[ TC], ppp = c0[ TC + 1];
        double wf  = wkl[idx];

        double d1 = pmp - pmm, d2 = p0p - p0m, d3 = ppp - ppm;
        double gx = (fma(d2, 2.0, d1) + d3) * wf;
        double e1 = ppm - pmm, e2 = pp0 - pm0, e3 = ppp - pmp;
        double gy = (fma(e2, 2.0, e1) + e3) * wf;

        double xs = gx + 1e-18;
        double m2 = fma(gx, gx, fma(gy, gy, 1e-18));

        // fast rsqrt: f32 HW seed + one f64 Newton (rel err ~5e-15)
        float  rf = rsqrtf((float)m2);
        double r0 = (double)rf;
        double tt = r0 * r0;
        double hm = m2 * 0.5;
        double r  = r0 * fma(-hm, tt, 1.5);
        double mag = m2 * r;

        // f32 sector estimate (octant-reduced deg-5 atan)
        float xf = (float)xs, yf = (float)gy;
        float ax = fabsf(xf), ay = fabsf(yf);
        float mn = fminf(ax, ay), mx = fmaxf(ax, ay);
        float rr = mn * __builtin_amdgcn_rcpf(mx);
        float s2 = rr * rr;
        float at = rr * fmaf(s2, fmaf(s2, 0.0792f, -0.2885f), 0.9954f);
        if (ay > ax)   at = 1.5707963f - at;
        if (xf < 0.0f) at = 3.1415927f - at;
        at = copysignf(at, yf);
        int n = (int)rintf(at * 5.7295780f);
        n = (n < -18) ? -18 : ((n > 18) ? 18 : n);

        // exact residual: rotate by -n*10deg, asin series
        double cn = ctab[n + 18];
        double sn = stab[n + 18];
        double yr = fma(gy, cn, -(xs * sn));
        double z  = yr * r;                  // sin(delta)
        double u  = z * z;
        double dl = z * fma(u, fma(u, fma(u, fma(u, 35.0 / 1152.0, 5.0 / 112.0),
                                          3.0 / 40.0), 1.0 / 6.0), 1.0);
        double phi = fma(dl, 5.729577951308232, (double)n);
        double fl  = floor(phi);
        double w1  = phi - fl;

        int bh = 54 + (int)fl;               // nominal [35,72]
        int b0 = bh - ((bh >= 36) ? 36 : 0);
        b0 = (b0 < 0) ? 0 : ((b0 > 35) ? 35 : b0);   // paranoia clamp
        int b1 = (b0 == 35) ? 0 : b0 + 1;

        double wo1 = w1 * mag;
        double wo0 = mag - wo1;
        int rep = lane & 1;
        atomicAdd(&hist[w][rep][b0], wo0);
        atomicAdd(&hist[w][rep][b1], wo1);
    }
    __syncthreads();

    // ---- merge replicas, /HW, circular smooth (f64) ----
    double hs_val = -INFINITY;
    if (lane < NBINS) {
        int im1 = (lane == 0) ? NBINS - 1 : lane - 1;
        int ip1 = (lane == NBINS - 1) ? 0 : lane + 1;
        double hm = hist[w][0][im1]  + hist[w][1][im1];
        double h0 = hist[w][0][lane] + hist[w][1][lane];
        double hp = hist[w][0][ip1]  + hist[w][1][ip1];
        hs_val = ((double)sw[0] * hm + (double)sw[1] * h0 + (double)sw[2] * hp)
                 * (1.0 / 1024.0);
        hsm[w][lane] = hs_val;
    }
    __syncthreads();

    // ---- argmax over 36 bins (first-occurrence tie-break) ----
    double v  = hs_val;
    int    bi = (lane < NBINS) ? lane : 64;
    #pragma unroll
    for (int sft = 32; sft > 0; sft >>= 1) {
        double ov = __shfl_xor(v, sft, 64);
        int    oi = __shfl_xor(bi, sft, 64);
        if (ov > v || (ov == v && oi < bi)) { v = ov; bi = oi; }
    }

    // ---- refinement + angle (lane 0 writes) ----
    if (lane == 0 && p < num_patches) {
        int ip = (bi == NBINS - 1) ? 0 : bi + 1;
        int im = (bi == 0) ? NBINS - 1 : bi - 1;
        double vp1 = hsm[w][ip];
        double vm1 = hsm[w][im];
        double refinement = ((vp1 - vm1) / 2.0) / (2.0 * v - (vp1 + vm1));
        double idx_ref = (double)bi + refinement;
        double angle = -((2.0 * M_PI * idx_ref) / 36.0 - M_PI);
        out[p] = (float)angle;
    }
}

extern "C" void kernel_launch(void* const* d_in, const int* in_sizes, int n_in,
                              void* d_out, int out_size, void* d_ws, size_t ws_size,
                              hipStream_t stream) {
    const float* patch = (const float*)d_in[0];
    const float* wk    = (const float*)d_in[1];
    const float* sw    = (const float*)d_in[2];
    float* out = (float*)d_out;

    int num_patches = in_sizes[0] / HW_N;          // 32768
    int blocks = (num_patches + WPB - 1) / WPB;    // 8192

    patch_dom_orient_kernel<<<blocks, 256, 0, stream>>>(patch, wk, sw, out, num_patches);
}

// Round 6
// 256.210 us; speedup vs baseline: 1.0714x; 1.0714x over previous
//
#include <hip/hip_runtime.h>
#include <math.h>

#define PATCH   32
#define NBINS   36
#define WPB     4           // waves (patches) per block
#define HW_N    (PATCH*PATCH)
#define TR      34          // padded rows: 0..33, interior 1..32
#define TC      36          // padded row stride (f32), cols 0..33 used
#define NREP    4           // histogram replicas (atomic spread)

// phi = atan2(gy, gx+1e-18) * 18/pi in (-18,18]; bin=(54+floor(phi))%36,
// w1=frac(phi). n = nearest 10-deg sector from f32 estimate (err ~0.01
// sector); exact f64 rotation by -n*10deg; sin(delta)=y'*rsqrt(m2); delta
// via deg-9 odd asin series. Total bin error ~1e-13; floor() absorbs the
// estimate error; bin-boundary flips are weight-continuous (harmless).

__global__ __launch_bounds__(256, 4) void patch_dom_orient_kernel(
    const float* __restrict__ patch,
    const float* __restrict__ wk,
    const float* __restrict__ sw,
    float* __restrict__ out,
    int num_patches)
{
    __shared__ float  tile[WPB][TR][TC];        // f32, edge-padded
    __shared__ double hist[WPB][NREP][NBINS];   // replicated
    __shared__ double hsm [WPB][NBINS];
    __shared__ double ctab[37];
    __shared__ double stab[37];

    const int tid  = threadIdx.x;
    const int w    = tid >> 6;
    const int lane = tid & 63;
    const int p    = blockIdx.x * WPB + w;
    const int pc   = (p < num_patches) ? p : (num_patches - 1);

    // ---- zero replicated histograms (144 doubles per wave) ----
    {
        double* hf = &hist[w][0][0];
        hf[lane] = 0.0;
        hf[64 + lane] = 0.0;
        if (lane < 16) hf[128 + lane] = 0.0;
    }
    // ---- sector sin/cos table (per block) ----
    if (tid < 37) {
        double a = ((double)tid - 18.0) * 0.17453292519943295;  // pi/18
        ctab[tid] = cos(a);
        stab[tid] = sin(a);
    }
    // ---- stage patch (f32) into padded tile interior ----
    const float4* pp4 = reinterpret_cast<const float4*>(patch + (size_t)pc * HW_N);
    #pragma unroll
    for (int i = 0; i < 4; ++i) {
        int idx4 = i * 64 + lane;            // 0..255
        float4 v = pp4[idx4];
        int flat = idx4 * 4;
        int row = flat >> 5;                 // 0..31
        int col = flat & 31;                 // 0,4,...,28
        float* dst = &tile[w][row + 1][col + 1];
        dst[0] = v.x; dst[1] = v.y; dst[2] = v.z; dst[3] = v.w;
    }
    // ---- edge duplication (clamp semantics); same-wave DS ops are ordered ----
    {
        int r = (lane >> 1) + 1;             // 1..32
        if (lane & 1) tile[w][r][33] = tile[w][r][32];
        else          tile[w][r][0]  = tile[w][r][1];
    }
    if (lane < 34) tile[w][0][lane]  = tile[w][1][lane];
    if (lane < 34) tile[w][33][lane] = tile[w][32][lane];
    __syncthreads();

    // ---- per-pixel: Sobel (f64 from f32 reads), sector-asin angle, scatter ----
    const float* tbase = &tile[w][0][0];
    #pragma unroll 2
    for (int i = 0; i < HW_N / 64; ++i) {
        int idx = i * 64 + lane;
        // &tile[w][y][x] = tbase + y*36 + x = tbase + idx + (idx>>5)*4
        const float* c0 = tbase + idx + ((idx >> 5) << 2);

        // 8 neighbors at immediate offsets (top-left corner layout)
        double pmm = (double)c0[0],      pm0 = (double)c0[1],      pmp = (double)c0[2];
        double p0m = (double)c0[TC],                               p0p = (double)c0[TC + 2];
        double ppm = (double)c0[2 * TC], pp0 = (double)c0[2 * TC + 1], ppp = (double)c0[2 * TC + 2];
        double wf  = (double)wk[idx] * 0.125;

        double d1 = pmp - pmm, d2 = p0p - p0m, d3 = ppp - pmp + (pmp - ppm);
        // keep exact same-form sums (order-insensitive at f64 for f32 inputs)
        d3 = ppp - ppm;
        double gx = (fma(d2, 2.0, d1) + d3) * wf;
        double e1 = ppm - pmm, e2 = pp0 - pm0, e3 = ppp - pmp;
        double gy = (fma(e2, 2.0, e1) + e3) * wf;

        double xs = gx + 1e-18;
        double m2 = fma(gx, gx, fma(gy, gy, 1e-18));

        // fast rsqrt: raw f32 HW seed + one f64 Newton (rel err ~1.5e-14)
        double r0 = (double)__builtin_amdgcn_rsqf((float)m2);
        double r  = r0 * fma(-(m2 * 0.5), r0 * r0, 1.5);
        double mag = m2 * r;

        // f32 sector estimate (octant-reduced deg-5 atan)
        float xf = (float)xs, yf = (float)gy;
        float ax = fabsf(xf), ay = fabsf(yf);
        float mn = fminf(ax, ay), mx = fmaxf(ax, ay);
        float rr = mn * __builtin_amdgcn_rcpf(mx);
        float s2 = rr * rr;
        float at = rr * fmaf(s2, fmaf(s2, 0.0792f, -0.2885f), 0.9954f);
        if (ay > ax)   at = 1.5707963f - at;
        if (xf < 0.0f) at = 3.1415927f - at;
        at = copysignf(at, yf);
        int n = (int)rintf(at * 5.7295780f);
        n = (n < -18) ? -18 : ((n > 18) ? 18 : n);

        // exact residual: rotate by -n*10deg, asin series
        double cn = ctab[n + 18];
        double sn = stab[n + 18];
        double yr = fma(gy, cn, -(xs * sn));
        double z  = yr * r;                  // sin(delta)
        double u  = z * z;
        double dl = z * fma(u, fma(u, fma(u, fma(u, 35.0 / 1152.0, 5.0 / 112.0),
                                          3.0 / 40.0), 1.0 / 6.0), 1.0);
        // ph2 = phi + 54 in (35.5, 72.5); trunc == floor (positive)
        double ph2 = fma(dl, 5.729577951308232, (double)(n + 54));
        int bh = (int)ph2;
        double w1 = ph2 - (double)bh;
        int b0 = bh - ((bh >= 36) ? 36 : 0);
        b0 = (b0 < 0) ? 0 : ((b0 > 35) ? 35 : b0);
        int b1 = (b0 == 35) ? 0 : b0 + 1;

        double wo1 = w1 * mag;
        double wo0 = mag - wo1;
        double* hrep = &hist[w][lane & (NREP - 1)][0];
        atomicAdd(&hrep[b0], wo0);
        atomicAdd(&hrep[b1], wo1);
    }
    __syncthreads();

    // ---- merge replicas, /HW, circular smooth (f64) ----
    double hs_val = -INFINITY;
    if (lane < NBINS) {
        int im1 = (lane == 0) ? NBINS - 1 : lane - 1;
        int ip1 = (lane == NBINS - 1) ? 0 : lane + 1;
        double hm = hist[w][0][im1]  + hist[w][1][im1]
                  + hist[w][2][im1]  + hist[w][3][im1];
        double h0 = hist[w][0][lane] + hist[w][1][lane]
                  + hist[w][2][lane] + hist[w][3][lane];
        double hp = hist[w][0][ip1]  + hist[w][1][ip1]
                  + hist[w][2][ip1]  + hist[w][3][ip1];
        hs_val = ((double)sw[0] * hm + (double)sw[1] * h0 + (double)sw[2] * hp)
                 * (1.0 / 1024.0);
        hsm[w][lane] = hs_val;
    }
    __syncthreads();

    // ---- argmax over 36 bins (first-occurrence tie-break) ----
    double v  = hs_val;
    int    bi = (lane < NBINS) ? lane : 64;
    #pragma unroll
    for (int sft = 32; sft > 0; sft >>= 1) {
        double ov = __shfl_xor(v, sft, 64);
        int    oi = __shfl_xor(bi, sft, 64);
        if (ov > v || (ov == v && oi < bi)) { v = ov; bi = oi; }
    }

    // ---- refinement + angle (lane 0 writes) ----
    if (lane == 0 && p < num_patches) {
        int ip = (bi == NBINS - 1) ? 0 : bi + 1;
        int im = (bi == 0) ? NBINS - 1 : bi - 1;
        double vp1 = hsm[w][ip];
        double vm1 = hsm[w][im];
        double refinement = ((vp1 - vm1) / 2.0) / (2.0 * v - (vp1 + vm1));
        double idx_ref = (double)bi + refinement;
        double angle = -((2.0 * M_PI * idx_ref) / 36.0 - M_PI);
        out[p] = (float)angle;
    }
}

extern "C" void kernel_launch(void* const* d_in, const int* in_sizes, int n_in,
                              void* d_out, int out_size, void* d_ws, size_t ws_size,
                              hipStream_t stream) {
    const float* patch = (const float*)d_in[0];
    const float* wk    = (const float*)d_in[1];
    const float* sw    = (const float*)d_in[2];
    float* out = (float*)d_out;

    int num_patches = in_sizes[0] / HW_N;          // 32768
    int blocks = (num_patches + WPB - 1) / WPB;    // 8192

    patch_dom_orient_kernel<<<blocks, 256, 0, stream>>>(patch, wk, sw, out, num_patches);
}

// Round 7
// 253.975 us; speedup vs baseline: 1.0809x; 1.0088x over previous
//
#include <hip/hip_runtime.h>
#include <math.h>

#define PATCH   32
#define NBINS   36
#define WPB     4           // waves (patches) per block
#define HW_N    (PATCH*PATCH)
#define TR      34          // padded rows: 0..33, interior 1..32
#define TC      34          // padded row stride (f32), cols 0..33
#define NREP    2           // histogram replicas

// phi = atan2(gy, gx+1e-18) * 18/pi in (-18,18]; bin=(54+floor(phi))%36,
// w1=frac(phi). n = nearest 10-deg sector from f32 estimate (err ~0.01
// sector); exact f64 rotation by -n*10deg; sin(delta)=y'*rsqrt(m2); delta
// via deg-9 odd asin series. Total bin error ~1e-13; floor() absorbs the
// estimate error; bin-boundary flips are weight-continuous (harmless).

__global__ __launch_bounds__(256, 7) void patch_dom_orient_kernel(
    const float* __restrict__ patch,
    const float* __restrict__ wk,
    const float* __restrict__ sw,
    float* __restrict__ out,
    int num_patches)
{
    __shared__ float  tile[WPB][TR][TC];        // f32, edge-padded; 18.5 KB
    __shared__ double hist[WPB][NREP][NBINS];   // 2.3 KB
    __shared__ double hsm [WPB][NBINS];         // 1.15 KB
    __shared__ double ctab[37];
    __shared__ double stab[37];

    const int tid  = threadIdx.x;
    const int w    = tid >> 6;
    const int lane = tid & 63;
    const int p    = blockIdx.x * WPB + w;
    const int pc   = (p < num_patches) ? p : (num_patches - 1);

    // ---- zero replicated histograms (72 doubles per wave) ----
    {
        double* hf = &hist[w][0][0];
        hf[lane] = 0.0;
        if (lane < 8) hf[64 + lane] = 0.0;
    }
    // ---- sector sin/cos table (per block) ----
    if (tid < 37) {
        double a = ((double)tid - 18.0) * 0.17453292519943295;  // pi/18
        ctab[tid] = cos(a);
        stab[tid] = sin(a);
    }
    // ---- stage patch (f32) into padded tile interior ----
    const float4* pp4 = reinterpret_cast<const float4*>(patch + (size_t)pc * HW_N);
    #pragma unroll
    for (int i = 0; i < 4; ++i) {
        int idx4 = i * 64 + lane;            // 0..255
        float4 v = pp4[idx4];
        int flat = idx4 * 4;
        int row = flat >> 5;                 // 0..31
        int col = flat & 31;                 // 0,4,...,28
        float* dst = &tile[w][row + 1][col + 1];
        dst[0] = v.x; dst[1] = v.y; dst[2] = v.z; dst[3] = v.w;
    }
    // ---- edge duplication (clamp semantics); wave-synchronous ordering ----
    {
        int r = (lane >> 1) + 1;             // 1..32
        if (lane & 1) tile[w][r][33] = tile[w][r][32];
        else          tile[w][r][0]  = tile[w][r][1];
    }
    if (lane < 34) tile[w][0][lane]  = tile[w][1][lane];
    if (lane < 34) tile[w][33][lane] = tile[w][32][lane];
    __syncthreads();

    // ---- per-pixel: f64 Sobel, sector-asin angle, 2-bin scatter ----
    const float* tbase = &tile[w][0][0];
    #pragma unroll 2
    for (int i = 0; i < HW_N / 64; ++i) {
        int idx = i * 64 + lane;
        // &tile[w][y][x] = tbase + y*34 + x = tbase + idx + 2*(idx>>5)
        const float* c0 = tbase + idx + ((idx >> 5) << 1);

        // 8 neighbors at immediate offsets (top-left corner layout)
        double pmm = (double)c0[0],      pm0 = (double)c0[1],          pmp = (double)c0[2];
        double p0m = (double)c0[TC],                                   p0p = (double)c0[TC + 2];
        double ppm = (double)c0[2 * TC], pp0 = (double)c0[2 * TC + 1], ppp = (double)c0[2 * TC + 2];
        double wf  = (double)wk[idx] * 0.125;

        double d1 = pmp - pmm, d2 = p0p - p0m, d3 = ppp - ppm;
        double gx = (fma(d2, 2.0, d1) + d3) * wf;
        double e1 = ppm - pmm, e2 = pp0 - pm0, e3 = ppp - pmp;
        double gy = (fma(e2, 2.0, e1) + e3) * wf;

        double xs = gx + 1e-18;
        double m2 = fma(gx, gx, fma(gy, gy, 1e-18));

        // fast rsqrt: raw f32 HW seed + one f64 Newton (rel err ~1.5e-14)
        double r0 = (double)__builtin_amdgcn_rsqf((float)m2);
        double r  = r0 * fma(-(m2 * 0.5), r0 * r0, 1.5);
        double mag = m2 * r;

        // f32 sector estimate (octant-reduced deg-5 atan)
        float xf = (float)xs, yf = (float)gy;
        float ax = fabsf(xf), ay = fabsf(yf);
        float mn = fminf(ax, ay), mx = fmaxf(ax, ay);
        float rr = mn * __builtin_amdgcn_rcpf(mx);
        float s2 = rr * rr;
        float at = rr * fmaf(s2, fmaf(s2, 0.0792f, -0.2885f), 0.9954f);
        if (ay > ax)   at = 1.5707963f - at;
        if (xf < 0.0f) at = 3.1415927f - at;
        at = copysignf(at, yf);
        int n = (int)rintf(at * 5.7295780f);
        n = (n < -18) ? -18 : ((n > 18) ? 18 : n);

        // exact residual: rotate by -n*10deg, asin series
        double cn = ctab[n + 18];
        double sn = stab[n + 18];
        double yr = fma(gy, cn, -(xs * sn));
        double z  = yr * r;                  // sin(delta)
        double u  = z * z;
        double dl = z * fma(u, fma(u, fma(u, fma(u, 35.0 / 1152.0, 5.0 / 112.0),
                                          3.0 / 40.0), 1.0 / 6.0), 1.0);
        // ph2 = phi + 54 in (35.5, 72.5); positive -> trunc == floor
        double ph2 = fma(dl, 5.729577951308232, (double)(n + 54));
        int bh = (int)ph2;
        double w1 = ph2 - floor(ph2);        // v_fract_f64
        int b0 = bh - ((bh >= 36) ? 36 : 0);
        b0 = (b0 < 0) ? 0 : ((b0 > 35) ? 35 : b0);
        int b1 = (b0 == 35) ? 0 : b0 + 1;

        double wo1 = w1 * mag;
        double wo0 = mag - wo1;
        double* hrep = &hist[w][lane & (NREP - 1)][0];
        atomicAdd(&hrep[b0], wo0);
        atomicAdd(&hrep[b1], wo1);
    }
    __syncthreads();

    // ---- merge replicas, /HW, circular smooth (f64) ----
    double hs_val = -INFINITY;
    if (lane < NBINS) {
        int im1 = (lane == 0) ? NBINS - 1 : lane - 1;
        int ip1 = (lane == NBINS - 1) ? 0 : lane + 1;
        double hm = hist[w][0][im1]  + hist[w][1][im1];
        double h0 = hist[w][0][lane] + hist[w][1][lane];
        double hp = hist[w][0][ip1]  + hist[w][1][ip1];
        hs_val = ((double)sw[0] * hm + (double)sw[1] * h0 + (double)sw[2] * hp)
                 * (1.0 / 1024.0);
        hsm[w][lane] = hs_val;
    }
    __syncthreads();

    // ---- argmax over 36 bins (first-occurrence tie-break) ----
    double v  = hs_val;
    int    bi = (lane < NBINS) ? lane : 64;
    #pragma unroll
    for (int sft = 32; sft > 0; sft >>= 1) {
        double ov = __shfl_xor(v, sft, 64);
        int    oi = __shfl_xor(bi, sft, 64);
        if (ov > v || (ov == v && oi < bi)) { v = ov; bi = oi; }
    }

    // ---- refinement + angle (lane 0 writes) ----
    if (lane == 0 && p < num_patches) {
        int ip = (bi == NBINS - 1) ? 0 : bi + 1;
        int im = (bi == 0) ? NBINS - 1 : bi - 1;
        double vp1 = hsm[w][ip];
        double vm1 = hsm[w][im];
        double refinement = ((vp1 - vm1) / 2.0) / (2.0 * v - (vp1 + vm1));
        double idx_ref = (double)bi + refinement;
        double angle = -((2.0 * M_PI * idx_ref) / 36.0 - M_PI);
        out[p] = (float)angle;
    }
}

extern "C" void kernel_launch(void* const* d_in, const int* in_sizes, int n_in,
                              void* d_out, int out_size, void* d_ws, size_t ws_size,
                              hipStream_t stream) {
    const float* patch = (const float*)d_in[0];
    const float* wk    = (const float*)d_in[1];
    const float* sw    = (const float*)d_in[2];
    float* out = (float*)d_out;

    int num_patches = in_sizes[0] / HW_N;          // 32768
    int blocks = (num_patches + WPB - 1) / WPB;    // 8192

    patch_dom_orient_kernel<<<blocks, 256, 0, stream>>>(patch, wk, sw, out, num_patches);
}

// Round 8
// 248.001 us; speedup vs baseline: 1.1069x; 1.0241x over previous
//
#include <hip/hip_runtime.h>
#include <math.h>

#define PATCH   32
#define NBINS   36
#define WPB     4           // waves (patches) per block
#define HW_N    (PATCH*PATCH)
#define TR      34          // padded rows: 0..33, interior 1..32
#define TC      34          // padded row stride (f32), cols 0..33
#define NREP    2           // histogram replicas

// phi = atan2(gy, gx+1e-18) * 18/pi in (-18,18]; bin=(54+floor(phi))%36,
// w1=frac(phi). n = nearest 10-deg sector from f32 estimate; exact f64
// rotation by -n*10deg; sin(delta)=y'*rsqrt(m2); delta via deg-9 odd asin
// series. Total bin error ~1e-13; floor() absorbs estimate error.
// Sobel via rolling row-sums: lane owns column c=lane&31, half h=lane>>5
// (rows h*16..h*16+15). T(r)=a+2b+c_, D(r)=c_-a over padded rows; then
// gx=(D(r-1)+2D(r)+D(r+1))*wf (bit-identical to prior form), gy=(T(r+1)-
// T(r-1))*wf (regrouped; ~1e-16 rel diff, harmless at 1e-12 budget).

__global__ __launch_bounds__(256, 7) void patch_dom_orient_kernel(
    const float* __restrict__ patch,
    const float* __restrict__ wk,
    const float* __restrict__ sw,
    float* __restrict__ out,
    int num_patches)
{
    __shared__ float  tile[WPB][TR][TC];        // f32, edge-padded; 18.5 KB
    __shared__ double hist[WPB][NREP][NBINS];   // 2.3 KB
    __shared__ double hsm [WPB][NBINS];         // 1.15 KB
    __shared__ double ctab[37];
    __shared__ double stab[37];

    const int tid  = threadIdx.x;
    const int w    = tid >> 6;
    const int lane = tid & 63;
    const int p    = blockIdx.x * WPB + w;
    const int pc   = (p < num_patches) ? p : (num_patches - 1);

    // ---- zero replicated histograms (72 doubles per wave) ----
    {
        double* hf = &hist[w][0][0];
        hf[lane] = 0.0;
        if (lane < 8) hf[64 + lane] = 0.0;
    }
    // ---- sector sin/cos table (per block) ----
    if (tid < 37) {
        double a = ((double)tid - 18.0) * 0.17453292519943295;  // pi/18
        ctab[tid] = cos(a);
        stab[tid] = sin(a);
    }
    // ---- stage patch (f32) into padded tile interior ----
    const float4* pp4 = reinterpret_cast<const float4*>(patch + (size_t)pc * HW_N);
    #pragma unroll
    for (int i = 0; i < 4; ++i) {
        int idx4 = i * 64 + lane;            // 0..255
        float4 v = pp4[idx4];
        int flat = idx4 * 4;
        int row = flat >> 5;                 // 0..31
        int col = flat & 31;                 // 0,4,...,28
        float* dst = &tile[w][row + 1][col + 1];
        dst[0] = v.x; dst[1] = v.y; dst[2] = v.z; dst[3] = v.w;
    }
    // ---- edge duplication (clamp semantics); wave-synchronous ordering ----
    {
        int r = (lane >> 1) + 1;             // 1..32
        if (lane & 1) tile[w][r][33] = tile[w][r][32];
        else          tile[w][r][0]  = tile[w][r][1];
    }
    if (lane < 34) tile[w][0][lane]  = tile[w][1][lane];
    if (lane < 34) tile[w][33][lane] = tile[w][32][lane];
    __syncthreads();

    // ---- per-pixel: rolling-row f64 Sobel, sector-asin angle, scatter ----
    {
        const int c  = lane & 31;            // owned column (pixel x = c)
        const int h  = lane >> 5;            // row-half
        const int r0 = h * 16;               // first padded row of window
        const float* rowp = &tile[w][r0][c];
        const float* wkp  = wk + r0 * 32 + c;
        double* hrep = &hist[w][lane & (NREP - 1)][0];

        // init: T/D at padded rows r0, r0+1
        double a0 = (double)rowp[0], b0v = (double)rowp[1], c0v = (double)rowp[2];
        double Tm = fma(b0v, 2.0, a0) + c0v;
        double Dm = c0v - a0;
        rowp += TC;
        double a1 = (double)rowp[0], b1v = (double)rowp[1], c1v = (double)rowp[2];
        double T0 = fma(b1v, 2.0, a1) + c1v;
        double D0 = c1v - a1;

        #pragma unroll 4
        for (int k = 0; k < 16; ++k) {
            rowp += TC;                      // padded row r0+k+2
            double ar = (double)rowp[0], br = (double)rowp[1], cr = (double)rowp[2];
            double Tp = fma(br, 2.0, ar) + cr;
            double Dp = cr - ar;

            double wf = (double)wkp[k * 32] * 0.125;
            double gx = (fma(D0, 2.0, Dm) + Dp) * wf;
            double gy = (Tp - Tm) * wf;

            double xs = gx + 1e-18;
            double m2 = fma(gx, gx, fma(gy, gy, 1e-18));

            // fast rsqrt: raw f32 HW seed + one f64 Newton (rel err ~1.5e-14)
            double r0v = (double)__builtin_amdgcn_rsqf((float)m2);
            double rr0 = r0v * fma(-(m2 * 0.5), r0v * r0v, 1.5);
            double mag = m2 * rr0;

            // f32 sector estimate (octant-reduced deg-5 atan)
            float xf = (float)xs, yf = (float)gy;
            float ax = fabsf(xf), ay = fabsf(yf);
            float mn = fminf(ax, ay), mx = fmaxf(ax, ay);
            float rq = mn * __builtin_amdgcn_rcpf(mx);
            float s2 = rq * rq;
            float at = rq * fmaf(s2, fmaf(s2, 0.0792f, -0.2885f), 0.9954f);
            if (ay > ax)   at = 1.5707963f - at;
            if (xf < 0.0f) at = 3.1415927f - at;
            at = copysignf(at, yf);
            int n = (int)rintf(at * 5.7295780f);
            n = (n < -18) ? -18 : ((n > 18) ? 18 : n);

            // exact residual: rotate by -n*10deg, asin series
            double cn = ctab[n + 18];
            double sn = stab[n + 18];
            double yr = fma(gy, cn, -(xs * sn));
            double z  = yr * rr0;            // sin(delta)
            double u  = z * z;
            double dl = z * fma(u, fma(u, fma(u, fma(u, 35.0 / 1152.0, 5.0 / 112.0),
                                              3.0 / 40.0), 1.0 / 6.0), 1.0);
            // ph2 = phi + 54 in (35.5, 72.5); positive -> trunc == floor
            double ph2 = fma(dl, 5.729577951308232, (double)(n + 54));
            int bh = (int)ph2;
            double w1 = ph2 - (double)bh;
            int b0 = bh;
            if (b0 >= 36) b0 -= 36;
            if (b0 >= 36) b0 -= 36;          // bh==72 (ori exactly pi) -> bin 0
            int b1 = (b0 == 35) ? 0 : b0 + 1;

            double wo1 = w1 * mag;
            double wo0 = mag - wo1;
            atomicAdd(&hrep[b0], wo0);
            atomicAdd(&hrep[b1], wo1);

            Tm = T0; T0 = Tp; Dm = D0; D0 = Dp;
        }
    }
    __syncthreads();

    // ---- merge replicas, /HW, circular smooth (f64) ----
    double hs_val = -INFINITY;
    if (lane < NBINS) {
        int im1 = (lane == 0) ? NBINS - 1 : lane - 1;
        int ip1 = (lane == NBINS - 1) ? 0 : lane + 1;
        double hm = hist[w][0][im1]  + hist[w][1][im1];
        double h0 = hist[w][0][lane] + hist[w][1][lane];
        double hp = hist[w][0][ip1]  + hist[w][1][ip1];
        hs_val = ((double)sw[0] * hm + (double)sw[1] * h0 + (double)sw[2] * hp)
                 * (1.0 / 1024.0);
        hsm[w][lane] = hs_val;
    }
    __syncthreads();

    // ---- argmax over 36 bins (first-occurrence tie-break) ----
    double v  = hs_val;
    int    bi = (lane < NBINS) ? lane : 64;
    #pragma unroll
    for (int sft = 32; sft > 0; sft >>= 1) {
        double ov = __shfl_xor(v, sft, 64);
        int    oi = __shfl_xor(bi, sft, 64);
        if (ov > v || (ov == v && oi < bi)) { v = ov; bi = oi; }
    }

    // ---- refinement + angle (lane 0 writes) ----
    if (lane == 0 && p < num_patches) {
        int ip = (bi == NBINS - 1) ? 0 : bi + 1;
        int im = (bi == 0) ? NBINS - 1 : bi - 1;
        double vp1 = hsm[w][ip];
        double vm1 = hsm[w][im];
        double refinement = ((vp1 - vm1) / 2.0) / (2.0 * v - (vp1 + vm1));
        double idx_ref = (double)bi + refinement;
        double angle = -((2.0 * M_PI * idx_ref) / 36.0 - M_PI);
        out[p] = (float)angle;
    }
}

extern "C" void kernel_launch(void* const* d_in, const int* in_sizes, int n_in,
                              void* d_out, int out_size, void* d_ws, size_t ws_size,
                              hipStream_t stream) {
    const float* patch = (const float*)d_in[0];
    const float* wk    = (const float*)d_in[1];
    const float* sw    = (const float*)d_in[2];
    float* out = (float*)d_out;

    int num_patches = in_sizes[0] / HW_N;          // 32768
    int blocks = (num_patches + WPB - 1) / WPB;    // 8192

    patch_dom_orient_kernel<<<blocks, 256, 0, stream>>>(patch, wk, sw, out, num_patches);
}

// Round 9
// 235.555 us; speedup vs baseline: 1.1654x; 1.0528x over previous
//
#include <hip/hip_runtime.h>
#include <math.h>

#define PATCH   32
#define NBINS   36
#define WPB     4           // waves (patches) per block
#define HW_N    (PATCH*PATCH)
#define TR      34          // padded rows: 0..33, interior 1..32
#define TC      34          // padded row stride (f32), cols 0..33
#define NREP    2           // histogram replicas

// Per-pixel pipeline in f32 (sector method keeps angle error ~1e-7, far
// better than the reference's own atan2f); accumulation in f64 LDS atomics
// (order-independent -> bin values = exact sum of per-pixel f32 values).
// w1 from the small residual s = dl*18/pi (f32 ulp ~3e-8 near 0), never
// from the ~50-magnitude ph2 (ulp 7.6e-6). Bin noise ~5e-6 absolute vs
// ~1e-4 flip boundary (R1 empirics) -> ~20x margin.
// Sobel via rolling row-sums: lane owns column c=lane&31, half h=lane>>5;
// T(r)=a+2b+c_, D(r)=c_-a; gx=(D(r-1)+2D(r)+D(r+1))*wf, gy=(T(r+1)-T(r-1))*wf.

__global__ __launch_bounds__(256, 7) void patch_dom_orient_kernel(
    const float* __restrict__ patch,
    const float* __restrict__ wk,
    const float* __restrict__ sw,
    float* __restrict__ out,
    int num_patches)
{
    __shared__ float  tile[WPB][TR][TC];        // f32, edge-padded; 18.5 KB
    __shared__ double hist[WPB][NREP][NBINS];   // 2.3 KB
    __shared__ double hsm [WPB][NBINS];         // 1.15 KB
    __shared__ float2 cstab[37];                // {cos,sin}(n*10deg)

    const int tid  = threadIdx.x;
    const int w    = tid >> 6;
    const int lane = tid & 63;
    const int p    = blockIdx.x * WPB + w;
    const int pc   = (p < num_patches) ? p : (num_patches - 1);

    // ---- zero replicated histograms (72 doubles per wave) ----
    {
        double* hf = &hist[w][0][0];
        hf[lane] = 0.0;
        if (lane < 8) hf[64 + lane] = 0.0;
    }
    // ---- sector cos/sin table (per block; f64 trig amortized) ----
    if (tid < 37) {
        double a = ((double)tid - 18.0) * 0.17453292519943295;  // pi/18
        cstab[tid] = make_float2((float)cos(a), (float)sin(a));
    }
    // ---- stage patch (f32) into padded tile interior ----
    const float4* pp4 = reinterpret_cast<const float4*>(patch + (size_t)pc * HW_N);
    #pragma unroll
    for (int i = 0; i < 4; ++i) {
        int idx4 = i * 64 + lane;            // 0..255
        float4 v = pp4[idx4];
        int flat = idx4 * 4;
        int row = flat >> 5;                 // 0..31
        int col = flat & 31;                 // 0,4,...,28
        float* dst = &tile[w][row + 1][col + 1];
        dst[0] = v.x; dst[1] = v.y; dst[2] = v.z; dst[3] = v.w;
    }
    // ---- edge duplication (clamp semantics); wave-synchronous ordering ----
    {
        int r = (lane >> 1) + 1;             // 1..32
        if (lane & 1) tile[w][r][33] = tile[w][r][32];
        else          tile[w][r][0]  = tile[w][r][1];
    }
    if (lane < 34) tile[w][0][lane]  = tile[w][1][lane];
    if (lane < 34) tile[w][33][lane] = tile[w][32][lane];
    __syncthreads();

    // ---- per-pixel: f32 rolling Sobel, sector angle, f64-atomic scatter ----
    {
        const int c  = lane & 31;            // owned column
        const int h  = lane >> 5;            // row-half
        const int r0 = h * 16;
        const float* rowp = &tile[w][r0][c];
        const float* wkp  = wk + r0 * 32 + c;
        double* hrep = &hist[w][lane & (NREP - 1)][0];

        float a0 = rowp[0], b0v = rowp[1], c0v = rowp[2];
        float Tm = fmaf(b0v, 2.0f, a0) + c0v;
        float Dm = c0v - a0;
        rowp += TC;
        float a1 = rowp[0], b1v = rowp[1], c1v = rowp[2];
        float T0 = fmaf(b1v, 2.0f, a1) + c1v;
        float D0 = c1v - a1;

        #pragma unroll 4
        for (int k = 0; k < 16; ++k) {
            rowp += TC;
            float ar = rowp[0], br = rowp[1], cr = rowp[2];
            float Tp = fmaf(br, 2.0f, ar) + cr;
            float Dp = cr - ar;

            float wf = wkp[k * 32] * 0.125f;
            float gx = (fmaf(D0, 2.0f, Dm) + Dp) * wf;
            float gy = (Tp - Tm) * wf;

            float xs = gx + 1e-18f;
            float m2 = fmaf(gx, gx, fmaf(gy, gy, 1e-18f));
            float r  = __builtin_amdgcn_rsqf(m2);   // ~1 ulp
            float mag = m2 * r;

            // sector estimate (octant-reduced deg-5 atan; err ~0.01 sector)
            float ax = fabsf(xs), ay = fabsf(gy);
            float mn = fminf(ax, ay), mx = fmaxf(ax, ay);
            mx = fmaxf(mx, 1e-30f);                 // guard 0/0 -> NaN
            float rq = mn * __builtin_amdgcn_rcpf(mx);
            float s2 = rq * rq;
            float at = rq * fmaf(s2, fmaf(s2, 0.0792f, -0.2885f), 0.9954f);
            if (ay > ax)    at = 1.5707963f - at;
            if (xs < 0.0f)  at = 3.1415927f - at;
            at = copysignf(at, gy);
            int n = (int)rintf(at * 5.7295780f);
            n = (n < -18) ? -18 : ((n > 18) ? 18 : n);

            // residual: rotate by -n*10deg; asin series through z^7
            float2 cs = cstab[n + 18];
            float yr = fmaf(gy, cs.x, -(xs * cs.y));
            float z  = yr * r;                      // sin(delta), |z|<=0.089
            float u  = z * z;
            float dl = z * fmaf(u, fmaf(u, fmaf(u, 0.044642857f, 0.075f),
                                        0.16666667f), 1.0f);
            float s  = dl * 5.7295780f;             // in (-0.51, 0.51)
            int neg  = (s < 0.0f) ? 1 : 0;
            float w1 = neg ? (s + 1.0f) : s;        // frac, ulp ~1e-7
            int bh   = n + 54 - neg;                // in [35, 72]
            int b0   = bh - ((bh >= 36) ? 36 : 0);
            b0       = b0 - ((b0 >= 36) ? 36 : 0);  // bh==72 -> bin 0
            int b1   = (b0 == 35) ? 0 : b0 + 1;

            float wo1 = w1 * mag;
            float wo0 = mag - wo1;
            atomicAdd(&hrep[b0], (double)wo0);
            atomicAdd(&hrep[b1], (double)wo1);

            Tm = T0; T0 = Tp; Dm = D0; D0 = Dp;
        }
    }
    __syncthreads();

    // ---- merge replicas, /HW, circular smooth (f64) ----
    double hs_val = -INFINITY;
    if (lane < NBINS) {
        int im1 = (lane == 0) ? NBINS - 1 : lane - 1;
        int ip1 = (lane == NBINS - 1) ? 0 : lane + 1;
        double hm = hist[w][0][im1]  + hist[w][1][im1];
        double h0 = hist[w][0][lane] + hist[w][1][lane];
        double hp = hist[w][0][ip1]  + hist[w][1][ip1];
        hs_val = ((double)sw[0] * hm + (double)sw[1] * h0 + (double)sw[2] * hp)
                 * (1.0 / 1024.0);
        hsm[w][lane] = hs_val;
    }
    __syncthreads();

    // ---- argmax over 36 bins (first-occurrence tie-break) ----
    double v  = hs_val;
    int    bi = (lane < NBINS) ? lane : 64;
    #pragma unroll
    for (int sft = 32; sft > 0; sft >>= 1) {
        double ov = __shfl_xor(v, sft, 64);
        int    oi = __shfl_xor(bi, sft, 64);
        if (ov > v || (ov == v && oi < bi)) { v = ov; bi = oi; }
    }

    // ---- refinement + angle (lane 0 writes) ----
    if (lane == 0 && p < num_patches) {
        int ip = (bi == NBINS - 1) ? 0 : bi + 1;
        int im = (bi == 0) ? NBINS - 1 : bi - 1;
        double vp1 = hsm[w][ip];
        double vm1 = hsm[w][im];
        double refinement = ((vp1 - vm1) / 2.0) / (2.0 * v - (vp1 + vm1));
        double idx_ref = (double)bi + refinement;
        double angle = -((2.0 * M_PI * idx_ref) / 36.0 - M_PI);
        out[p] = (float)angle;
    }
}

extern "C" void kernel_launch(void* const* d_in, const int* in_sizes, int n_in,
                              void* d_out, int out_size, void* d_ws, size_t ws_size,
                              hipStream_t stream) {
    const float* patch = (const float*)d_in[0];
    const float* wk    = (const float*)d_in[1];
    const float* sw    = (const float*)d_in[2];
    float* out = (float*)d_out;

    int num_patches = in_sizes[0] / HW_N;          // 32768
    int blocks = (num_patches + WPB - 1) / WPB;    // 8192

    patch_dom_orient_kernel<<<blocks, 256, 0, stream>>>(patch, wk, sw, out, num_patches);
}